// Round 1
// baseline (184.369 us; speedup 1.0000x reference)
//
#include <hip/hip_runtime.h>
#include <hip/hip_bf16.h>

// out[b,c,hw] = sum_t x[b,t,c,hw] * W[c,t] + bias[c]
// B=16, T=10, C=1024, HW=196 (=49 float4s)
// x strides (floats): b: T*C*HW, t: C*HW, c: HW, hw: 1
// Memory-bound: ~141 MB traffic -> ~22us floor @6.3TB/s.

#define T_IN   10
#define C_MAPS 1024
#define HW4    49            // 196/4 float4s per map
#define C_HW4  (C_MAPS * HW4)  // float4s per (b,t) plane = 50176

__global__ __launch_bounds__(256) void conv_over_time_kernel(
    const float* __restrict__ x,
    const float* __restrict__ Wmat,
    const float* __restrict__ bias,
    float* __restrict__ out)
{
    const int idx4 = blockIdx.x * blockDim.x + threadIdx.x;  // float4 output index
    // idx4 in [0, B*C_HW4) ; grid sized exactly.

    const int b   = idx4 / C_HW4;
    const int rem = idx4 - b * C_HW4;
    const int c   = rem / HW4;

    const float4* __restrict__ x4 = (const float4*)x;
    const long base = (long)b * T_IN * C_HW4 + rem;

    const float* __restrict__ wrow = Wmat + c * T_IN;

    const float bb = bias[c];
    float4 acc = make_float4(bb, bb, bb, bb);

#pragma unroll
    for (int t = 0; t < T_IN; ++t) {
        const float4 v = x4[base + (long)t * C_HW4];
        const float  w = wrow[t];
        acc.x = fmaf(v.x, w, acc.x);
        acc.y = fmaf(v.y, w, acc.y);
        acc.z = fmaf(v.z, w, acc.z);
        acc.w = fmaf(v.w, w, acc.w);
    }

    ((float4*)out)[idx4] = acc;
}

extern "C" void kernel_launch(void* const* d_in, const int* in_sizes, int n_in,
                              void* d_out, int out_size, void* d_ws, size_t ws_size,
                              hipStream_t stream) {
    const float* x    = (const float*)d_in[0];  // [16,10,1024,14,14]
    const float* Wmat = (const float*)d_in[1];  // [1024,10]
    const float* bias = (const float*)d_in[2];  // [1024]
    float* out = (float*)d_out;                 // [16,1,1024,14,14]

    const int total4 = 16 * C_HW4;              // 802816 float4 outputs
    const int block  = 256;
    const int grid   = total4 / block;          // 3136 exactly

    conv_over_time_kernel<<<grid, block, 0, stream>>>(x, Wmat, bias, out);
}